// Round 1
// baseline (206.150 us; speedup 1.0000x reference)
//
#include <hip/hip_runtime.h>
#include <hip/hip_bf16.h>

// Problem constants (reference: N=16384, C=2048, F=512; fp32 in/out).
constexpr int N_ROWS = 16384;
constexpr int C_CLS  = 2048;
constexpr int F_DIM  = 512;

typedef __bf16 bf16x8 __attribute__((ext_vector_type(8)));
typedef float  f32x4  __attribute__((ext_vector_type(4)));

// ---------------------------------------------------------------------------
// Pre-pass: per-row fp32 -> bf16 conversion + exact fp32 row sum-of-squares.
// One block (256 threads) per row of F=512 floats (float2 per thread).
// ---------------------------------------------------------------------------
__global__ __launch_bounds__(256) void prep_rows(
    const float* __restrict__ src,
    __hip_bfloat162* __restrict__ dst,   // row stride = 256 bf162 (= 512 bf16)
    float* __restrict__ sq)
{
    const int row = blockIdx.x;
    const int tid = threadIdx.x;
    const float2 v = ((const float2*)(src + (size_t)row * F_DIM))[tid];

    __hip_bfloat162 p;
    p.x = __float2bfloat16(v.x);
    p.y = __float2bfloat16(v.y);
    dst[(size_t)row * (F_DIM / 2) + tid] = p;

    float ss = v.x * v.x + v.y * v.y;
    #pragma unroll
    for (int off = 32; off > 0; off >>= 1) ss += __shfl_down(ss, off);

    __shared__ float red[4];
    if ((tid & 63) == 0) red[tid >> 6] = ss;
    __syncthreads();
    if (tid == 0) sq[row] = red[0] + red[1] + red[2] + red[3];
}

// ---------------------------------------------------------------------------
// bf16 MFMA GEMM-BT with fused NCM epilogue.
// out[n][c] = -sqrt(max(xsq[n] + msq[c] - 2 * sum_f xb[n,f]*mb[c,f], 0))
// 128x128 block tile, BK=64, 256 threads = 4 waves in 2x2, each wave 64x64
// via 4x4 grid of 16x16x32 bf16 MFMA tiles.
// LDS staged via global_load_lds (16B/lane); chunk-XOR swizzle to avoid
// ds_read_b128 bank aliasing: data chunk c of row r sits at position c^(r&7).
// ---------------------------------------------------------------------------
__device__ __forceinline__ void async_copy16(const __hip_bfloat16* g,
                                             __hip_bfloat16* l)
{
    __builtin_amdgcn_global_load_lds(
        (const __attribute__((address_space(1))) unsigned int*)g,
        (__attribute__((address_space(3))) unsigned int*)l,
        16, 0, 0);
}

__global__ __launch_bounds__(256) void ncm_gemm(
    const __hip_bfloat16* __restrict__ xb,   // [N, F] bf16
    const __hip_bfloat16* __restrict__ mb,   // [C, F] bf16
    const float* __restrict__ xsq,           // [N]
    const float* __restrict__ msq,           // [C]
    float* __restrict__ out)                 // [N, C] fp32
{
    constexpr int BM = 128, BN = 128, BK = 64;

    __shared__ alignas(16) __hip_bfloat16 sA[BM * BK];  // 16 KB
    __shared__ alignas(16) __hip_bfloat16 sB[BN * BK];  // 16 KB

    const int tid  = threadIdx.x;
    const int wave = tid >> 6;        // 0..3
    const int lane = tid & 63;
    const int wm   = wave >> 1;       // wave row (2x2)
    const int wn   = wave & 1;        // wave col

    const int row0 = blockIdx.y * BM; // over N (x rows)
    const int col0 = blockIdx.x * BN; // over C (means rows)

    // ---- staging addressing (global side carries the swizzle) ----
    // lane l of each instruction: row = base + (l>>3), data chunk = (l&7)^(l>>3)
    const int srow  = lane >> 3;                       // 0..7
    const int schunk = (lane & 7) ^ srow;              // swizzled chunk id
    const int scol  = schunk * 8;                      // element offset in row

    const __hip_bfloat16* gA =
        xb + (size_t)(row0 + wave * 32 + srow) * F_DIM + scol;
    const __hip_bfloat16* gB =
        mb + (size_t)(col0 + wave * 32 + srow) * F_DIM + scol;

    f32x4 acc[4][4] = {};

    const int lm   = lane & 15;   // A row / B row (=n) within 16-tile
    const int quad = lane >> 4;   // 0..3

    for (int kt = 0; kt < F_DIM / BK; ++kt) {
        const int k0 = kt * BK;
        // each wave stages 32 rows of A and 32 rows of B (4+4 instructions)
        #pragma unroll
        for (int i = 0; i < 4; ++i) {
            async_copy16(gA + (size_t)i * 8 * F_DIM + k0,
                         &sA[(wave * 32 + i * 8) * BK]);
            async_copy16(gB + (size_t)i * 8 * F_DIM + k0,
                         &sB[(wave * 32 + i * 8) * BK]);
        }
        __syncthreads();   // drains vmcnt (global_load_lds) + lgkm

        #pragma unroll
        for (int h = 0; h < 2; ++h) {
            // k-chunk (8 bf16) index this quad needs, then swizzled position:
            // stored position = kchunk ^ (row&7); row&7 == lane&7 here.
            const int pos = (((h * 4 + quad) ^ (lane & 7)) * 8);
            bf16x8 af[4], bfr[4];
            #pragma unroll
            for (int i = 0; i < 4; ++i)
                af[i] = *(const bf16x8*)&sA[(wm * 64 + i * 16 + lm) * BK + pos];
            #pragma unroll
            for (int j = 0; j < 4; ++j)
                bfr[j] = *(const bf16x8*)&sB[(wn * 64 + j * 16 + lm) * BK + pos];
            #pragma unroll
            for (int i = 0; i < 4; ++i)
                #pragma unroll
                for (int j = 0; j < 4; ++j)
                    acc[i][j] = __builtin_amdgcn_mfma_f32_16x16x32_bf16(
                        af[i], bfr[j], acc[i][j], 0, 0, 0);
        }
        __syncthreads();
    }

    // ---- epilogue: C/D layout col = lane&15, row = quad*4 + reg ----
    float xs[4][4];
    #pragma unroll
    for (int i = 0; i < 4; ++i)
        #pragma unroll
        for (int r = 0; r < 4; ++r)
            xs[i][r] = xsq[row0 + wm * 64 + i * 16 + quad * 4 + r];

    #pragma unroll
    for (int j = 0; j < 4; ++j) {
        const int col = col0 + wn * 64 + j * 16 + lm;
        const float ms = msq[col];
        #pragma unroll
        for (int i = 0; i < 4; ++i) {
            const int rbase = row0 + wm * 64 + i * 16 + quad * 4;
            #pragma unroll
            for (int r = 0; r < 4; ++r) {
                const float d2 =
                    fmaxf(xs[i][r] + ms - 2.0f * acc[i][j][r], 0.0f);
                out[(size_t)(rbase + r) * C_CLS + col] = -sqrtf(d2);
            }
        }
    }
}

// ---------------------------------------------------------------------------
extern "C" void kernel_launch(void* const* d_in, const int* in_sizes, int n_in,
                              void* d_out, int out_size, void* d_ws,
                              size_t ws_size, hipStream_t stream)
{
    const float* x     = (const float*)d_in[0];   // [N, F]
    const float* means = (const float*)d_in[1];   // [C, F]
    float* out = (float*)d_out;                   // [N, C]

    char* ws = (char*)d_ws;
    __hip_bfloat16* xb = (__hip_bfloat16*)ws;                         // 16 MB
    __hip_bfloat16* mb = (__hip_bfloat16*)(ws + (size_t)N_ROWS * F_DIM * 2);
    float* xsq = (float*)(ws + (size_t)(N_ROWS + C_CLS) * F_DIM * 2);
    float* msq = xsq + N_ROWS;

    prep_rows<<<N_ROWS, 256, 0, stream>>>(x, (__hip_bfloat162*)xb, xsq);
    prep_rows<<<C_CLS, 256, 0, stream>>>(means, (__hip_bfloat162*)mb, msq);

    dim3 grid(C_CLS / 128, N_ROWS / 128);
    ncm_gemm<<<grid, 256, 0, stream>>>(xb, mb, xsq, msq, out);
}